// Round 16
// baseline (40.432 us; speedup 1.0000x reference)
//
#include <hip/hip_runtime.h>

typedef __attribute__((ext_vector_type(4))) float f32x4;
typedef __attribute__((ext_vector_type(16))) float f32x16;
typedef __attribute__((ext_vector_type(8))) _Float16 f16x8;

#define D_ 64
#define K_ 512

// 2-limb f16 on mfma_f32_32x32x16_f16, K extended with an esq block:
//   kb 0-3: hi limbs of dims 16kb..16kb+15 ; kb 4-7: lo limbs ; kb 8: esq
//   (p=0 -> hi(0.5||e||^2), p=1 -> lo, rest 0; query side = 1.0 at p=0,1).
// Operand slot p = (lane>>5)*8 + s, IDENTICAL builder on entry (A) and query
// (B) side => within-k-block permutation cancels (validated r15, absmax 0.0).
// Queries NEGATED in kb0-7 => acc = 0.5||e||^2 - c.e with C seed 0.
// C/D (HW m74/m101): col = lane&31 = query, row = (reg&3)+8*(reg>>2)+4*(lane>>5).
//
// OWNERSHIP FLIP vs r8-r15: wave w owns QUERIES 32w..32w+31 in registers;
// entries stream from a 144 KB LDS frag image. Each lane keeps the running
// argmin of its own query over all 512 entries -> after the sweep ONE
// shfl_xor(32) finishes; wave writes its own 32 output rows immediately.
// No cross-wave combine, no smin/simin, exactly ONE barrier in the kernel.
__global__ __launch_bounds__(512, 2)
void vq_fused(const float* __restrict__ codes,
              const float* __restrict__ codebook,
              float* __restrict__ out) {
  __shared__ _Float16 Ef[16 * 9 * 512];   // 144 KB: tile*4608 + kb*512 + p8*256 + r*8 + s

  const int t = threadIdx.x;
  const int w = t >> 6, l = t & 63;
  const int l32 = l & 31, lhi = l >> 5;
  const long long qb = (long long)blockIdx.x * 256;
  const long long myq = qb + w * 32 + l32;

  // ---- issue own-query loads first (HBM hides under entry staging) ----
  // lane needs dims kb*16 + lhi*8 + {0..7} for kb=0..3
  const float* qsrc = codes + myq * D_ + lhi * 8;
  f32x4 qv[8];
#pragma unroll
  for (int kb = 0; kb < 4; ++kb) {
    qv[2 * kb] = *(const f32x4*)(qsrc + kb * 16);
    qv[2 * kb + 1] = *(const f32x4*)(qsrc + kb * 16 + 4);
  }

  // ---- stage all 512 entries: thread t -> entry t ----
  {
    const float* src = codebook + t * D_;
    float es = 0.f;
    _Float16 hi[64], lo[64];
#pragma unroll
    for (int g = 0; g < 16; ++g) {
      f32x4 v = *(const f32x4*)(src + 4 * g);
#pragma unroll
      for (int j = 0; j < 4; ++j) {
        float a = v[j];
        es += a * a;
        _Float16 h = (_Float16)a;
        hi[4 * g + j] = h;
        lo[4 * g + j] = (_Float16)(a - (float)h);
      }
    }
    const int tile = t >> 5, r = t & 31;
    _Float16* dst = Ef + tile * 4608 + r * 8;
#pragma unroll
    for (int kb = 0; kb < 4; ++kb)
#pragma unroll
      for (int ph = 0; ph < 2; ++ph) {
        f16x8 wh, wl;
#pragma unroll
        for (int s = 0; s < 8; ++s) {
          wh[s] = hi[kb * 16 + ph * 8 + s];
          wl[s] = lo[kb * 16 + ph * 8 + s];
        }
        *(f16x8*)(dst + kb * 512 + ph * 256) = wh;        // hi limb
        *(f16x8*)(dst + (4 + kb) * 512 + ph * 256) = wl;  // lo limb
      }
    const float eh2 = 0.5f * es;
    const _Float16 eh = (_Float16)eh2;
    const _Float16 el = (_Float16)(eh2 - (float)eh);
    f16x8 w0 = (f16x8){eh, el, 0, 0, 0, 0, 0, 0};
    f16x8 w1 = (f16x8){0, 0, 0, 0, 0, 0, 0, 0};
    *(f16x8*)(dst + 8 * 512) = w0;                        // esq k-block
    *(f16x8*)(dst + 8 * 512 + 256) = w1;
  }
  __syncthreads();                        // the ONLY block-wide barrier

  // ---- build own-query frags (negated 2-limb) ----
  f16x8 qfh[4], qfl[4];
#pragma unroll
  for (int kb = 0; kb < 4; ++kb)
#pragma unroll
    for (int s = 0; s < 8; ++s) {
      float na = -qv[2 * kb + (s >> 2)][s & 3];
      _Float16 h = (_Float16)na;
      qfh[kb][s] = h;
      qfl[kb][s] = (_Float16)(na - (float)h);
    }
  f16x8 qfe = (f16x8){0, 0, 0, 0, 0, 0, 0, 0};
  if (lhi == 0) { qfe[0] = (_Float16)1.0f; qfe[1] = (_Float16)1.0f; }

  // ---- sweep 16 e-tiles, 2 at a time, barrier-free ----
  float mv = 3.4e38f; int mi = 0;
  for (int et = 0; et < 16; et += 2) {
    f16x8 ef0[9], ef1[9];
    const _Float16* b0 = Ef + et * 4608 + lhi * 256 + l32 * 8;
#pragma unroll
    for (int kb = 0; kb < 9; ++kb) {
      ef0[kb] = *(const f16x8*)(b0 + kb * 512);
      ef1[kb] = *(const f16x8*)(b0 + 4608 + kb * 512);
    }
    f32x16 a0, a1;
#pragma unroll
    for (int z = 0; z < 16; ++z) { a0[z] = 0.f; a1[z] = 0.f; }
    a0 = __builtin_amdgcn_mfma_f32_32x32x16_f16(ef0[8], qfe, a0, 0, 0, 0);  // +0.5||e||^2
    a1 = __builtin_amdgcn_mfma_f32_32x32x16_f16(ef1[8], qfe, a1, 0, 0, 0);
#pragma unroll
    for (int kb = 0; kb < 4; ++kb) {      // eh . (-ch)
      a0 = __builtin_amdgcn_mfma_f32_32x32x16_f16(ef0[kb], qfh[kb], a0, 0, 0, 0);
      a1 = __builtin_amdgcn_mfma_f32_32x32x16_f16(ef1[kb], qfh[kb], a1, 0, 0, 0);
    }
#pragma unroll
    for (int kb = 0; kb < 4; ++kb) {      // eh . (-cl)
      a0 = __builtin_amdgcn_mfma_f32_32x32x16_f16(ef0[kb], qfl[kb], a0, 0, 0, 0);
      a1 = __builtin_amdgcn_mfma_f32_32x32x16_f16(ef1[kb], qfl[kb], a1, 0, 0, 0);
    }
#pragma unroll
    for (int kb = 0; kb < 4; ++kb) {      // el . (-ch)
      a0 = __builtin_amdgcn_mfma_f32_32x32x16_f16(ef0[4 + kb], qfh[kb], a0, 0, 0, 0);
      a1 = __builtin_amdgcn_mfma_f32_32x32x16_f16(ef1[4 + kb], qfh[kb], a1, 0, 0, 0);
    }
    // in-lane argmin fold; rows ascending within each chain, tiles ascending
#pragma unroll
    for (int g = 0; g < 4; ++g)
#pragma unroll
      for (int r = 0; r < 4; ++r) {
        const int e0 = et * 32 + 8 * g + 4 * lhi + r;
        if (a0[4 * g + r] < mv) { mv = a0[4 * g + r]; mi = e0; }
      }
#pragma unroll
    for (int g = 0; g < 4; ++g)
#pragma unroll
      for (int r = 0; r < 4; ++r) {
        const int e1 = (et + 1) * 32 + 8 * g + 4 * lhi + r;
        if (a1[4 * g + r] < mv) { mv = a1[4 * g + r]; mi = e1; }
      }
  }
  // combine the two lane-halves (same query col, disjoint rows; tie -> lower idx)
  {
    float ov = __shfl_xor(mv, 32, 64);
    int oi = __shfl_xor(mi, 32, 64);
    if (ov < mv || (ov == mv && oi < mi)) { mv = ov; mi = oi; }
  }

  // ---- per-wave epilogue: gather exact fp32 row, write own output ----
  {
    const float* src = codebook + mi * D_ + lhi * 32;
    float* dst = out + myq * D_ + lhi * 32;
#pragma unroll
    for (int g = 0; g < 8; ++g) {
      f32x4 v = *(const f32x4*)(src + 4 * g);
      __builtin_nontemporal_store(v, (f32x4*)(dst + 4 * g));
    }
  }
}

extern "C" void kernel_launch(void* const* d_in, const int* in_sizes, int n_in,
                              void* d_out, int out_size, void* d_ws, size_t ws_size,
                              hipStream_t stream) {
  const float* codes = (const float*)d_in[0];
  const float* codebook = (const float*)d_in[1];
  float* out = (float*)d_out;
  const int Q = in_sizes[0] / D_;        // 65536
  const int grid = Q / 256;              // 256
  vq_fused<<<grid, 512, 0, stream>>>(codes, codebook, out);
}

// Round 17
// 25.497 us; speedup vs baseline: 1.5858x; 1.5858x over previous
//
#include <hip/hip_runtime.h>

typedef __attribute__((ext_vector_type(4))) float f32x4;
typedef __attribute__((ext_vector_type(16))) float f32x16;
typedef __attribute__((ext_vector_type(8))) _Float16 f16x8;

#define D_ 64
#define K_ 512

// 2-limb f16 (a = hi + lo, 22 mantissa bits) on mfma_f32_32x32x16_f16.
// K-space = 128 limbs in 8 k-blocks of 16: kb 0-3 = hi(dims 16kb..16kb+15),
// kb 4-7 = lo. Operand slot (lane>>5, s) holds dim-pos (lane>>5)*8 + s —
// IDENTICAL builder for entries (A) and queries (B), so any mismatch vs the
// true HW k-mapping cancels in A.B (validated r15/r16: absmax 0.0).
// Queries NEGATED; acc seeded with 0.5||e||^2: score = 0.5||e||^2 - c.e
// (lo.lo dropped, ~1.5e-5).
// C/D (HW m74/m101): col = lane&31 = query, row = (reg&3)+8*(reg>>2)+4*(lane>>5).
//
// r17 = r15 + FOUR independent MFMA chains per wave (split each tile's 12
// products by k-blocks {0,1} / {2,3} into two accumulators, one add at the
// end). 8 streams/SIMD attacks the dep-stall gap (loop ran at ~50% of its
// 5.1us MFMA floor with only 4 streams).
__global__ __launch_bounds__(512, 2)
void vq_fused(const float* __restrict__ codes,
              const float* __restrict__ codebook,
              float* __restrict__ out) {
  __shared__ _Float16 Af[256 * 128];     // 64 KB query frags
  __shared__ float esq_s[K_];            // 2 KB
  __shared__ float smin[8][256];         // 8 KB
  __shared__ int   simin[8][256];        // 8 KB
  __shared__ int   best[256];            // 1 KB

  const int t = threadIdx.x;
  const int w = t >> 6, l = t & 63;
  const int l32 = l & 31, lhi = l >> 5;
  const long long qb = (long long)blockIdx.x * 256;

  // ---- issue query loads first: thread -> query ql, dims dhalf..dhalf+31 ----
  const int ql = t >> 1, dhalf = (t & 1) * 32;
  const float* asrc = codes + (qb + ql) * D_ + dhalf;
  f32x4 av[8];
#pragma unroll
  for (int g = 0; g < 8; ++g) av[g] = *(const f32x4*)(asrc + 4 * g);

  // ---- build ef frags + 0.5||e||^2 (wave owns entries 64w..64w+63) ----
  f16x8 ef[2][8];                        // [tile][kb] kb0-3 hi, kb4-7 lo
#pragma unroll
  for (int i = 0; i < 2; ++i) {
    const int e = w * 64 + i * 32 + l32;
    float es = 0.f;
#pragma unroll
    for (int kb = 0; kb < 4; ++kb) {
      const float* src = codebook + e * D_ + kb * 16 + lhi * 8;
      f32x4 v0 = *(const f32x4*)src;
      f32x4 v1 = *(const f32x4*)(src + 4);
#pragma unroll
      for (int s = 0; s < 8; ++s) {
        float a = (s < 4) ? v0[s & 3] : v1[s & 3];
        es += a * a;
        _Float16 h = (_Float16)a;
        ef[i][kb][s] = h;
        ef[i][4 + kb][s] = (_Float16)(a - (float)h);
      }
    }
    es += __shfl_xor(es, 32, 64);        // lane pair covers all 64 dims
    if (lhi == 0) esq_s[e] = 0.5f * es;
  }

  // ---- stage queries: negated 2-limb frags, 8 x ds_write_b128 ----
  {
    const int kbs = (t & 1) * 2;         // thread's two k-blocks
    const int qtile = ql >> 5, qr = ql & 31;
#pragma unroll
    for (int kk = 0; kk < 2; ++kk)
#pragma unroll
      for (int ph = 0; ph < 2; ++ph) {
        f16x8 wh, wl;
#pragma unroll
        for (int s = 0; s < 8; ++s) {
          float na = -av[kk * 4 + ph * 2 + (s >> 2)][s & 3];
          _Float16 h = (_Float16)na;
          wh[s] = h;
          wl[s] = (_Float16)(na - (float)h);
        }
        _Float16* dst = Af + qtile * 4096 + (kbs + kk) * 512 + ph * 256 + qr * 8;
        *(f16x8*)dst = wh;               // hi k-block
        *(f16x8*)(dst + 2048) = wl;      // lo k-block (kb+4)
      }
  }
  __syncthreads();                       // barrier #1: Af + esq_s ready

  // per-lane 0.5||e||^2 for C/D rows: row(reg) = (reg&3) + 8*(reg>>2) + 4*lhi
  f32x4 esqr[2][4];
#pragma unroll
  for (int i = 0; i < 2; ++i)
#pragma unroll
    for (int g = 0; g < 4; ++g)
      esqr[i][g] = *(const f32x4*)(esq_s + w * 64 + i * 32 + 8 * g + 4 * lhi);

  // ---- main loop: 8 q-tiles of 32 queries, barrier-free ----
  for (int qt = 0; qt < 8; ++qt) {
    f16x8 qf[8];
#pragma unroll
    for (int kb = 0; kb < 8; ++kb)
      qf[kb] = *(const f16x8*)(&Af[qt * 4096 + kb * 512 + lhi * 256 + l32 * 8]);

    // FOUR independent MFMA chains: (tile, kb-half) in {0,1} x {01, 23}
    f32x16 a0A, a0B, a1A, a1B;
#pragma unroll
    for (int g = 0; g < 4; ++g)
#pragma unroll
      for (int r = 0; r < 4; ++r) {
        a0A[4 * g + r] = esqr[0][g][r];  // C seed: 0.5||e||^2 (A half only)
        a1A[4 * g + r] = esqr[1][g][r];
        a0B[4 * g + r] = 0.f;
        a1B[4 * g + r] = 0.f;
      }

#pragma unroll
    for (int kk = 0; kk < 2; ++kk) {     // hh: eh . (-ch)
      a0A = __builtin_amdgcn_mfma_f32_32x32x16_f16(ef[0][kk], qf[kk], a0A, 0, 0, 0);
      a1A = __builtin_amdgcn_mfma_f32_32x32x16_f16(ef[1][kk], qf[kk], a1A, 0, 0, 0);
      a0B = __builtin_amdgcn_mfma_f32_32x32x16_f16(ef[0][2 + kk], qf[2 + kk], a0B, 0, 0, 0);
      a1B = __builtin_amdgcn_mfma_f32_32x32x16_f16(ef[1][2 + kk], qf[2 + kk], a1B, 0, 0, 0);
    }
#pragma unroll
    for (int kk = 0; kk < 2; ++kk) {     // eh . (-cl)
      a0A = __builtin_amdgcn_mfma_f32_32x32x16_f16(ef[0][kk], qf[4 + kk], a0A, 0, 0, 0);
      a1A = __builtin_amdgcn_mfma_f32_32x32x16_f16(ef[1][kk], qf[4 + kk], a1A, 0, 0, 0);
      a0B = __builtin_amdgcn_mfma_f32_32x32x16_f16(ef[0][2 + kk], qf[6 + kk], a0B, 0, 0, 0);
      a1B = __builtin_amdgcn_mfma_f32_32x32x16_f16(ef[1][2 + kk], qf[6 + kk], a1B, 0, 0, 0);
    }
#pragma unroll
    for (int kk = 0; kk < 2; ++kk) {     // el . (-ch)
      a0A = __builtin_amdgcn_mfma_f32_32x32x16_f16(ef[0][4 + kk], qf[kk], a0A, 0, 0, 0);
      a1A = __builtin_amdgcn_mfma_f32_32x32x16_f16(ef[1][4 + kk], qf[kk], a1A, 0, 0, 0);
      a0B = __builtin_amdgcn_mfma_f32_32x32x16_f16(ef[0][6 + kk], qf[2 + kk], a0B, 0, 0, 0);
      a1B = __builtin_amdgcn_mfma_f32_32x32x16_f16(ef[1][6 + kk], qf[2 + kk], a1B, 0, 0, 0);
    }

    // merge halves, then per-lane argmin over 32 rows (ascending entry order)
    float mv = 3.4e38f; int mi = 0;
#pragma unroll
    for (int g = 0; g < 4; ++g)
#pragma unroll
      for (int r = 0; r < 4; ++r) {
        const float s0 = a0A[4 * g + r] + a0B[4 * g + r];
        const int e0 = w * 64 + 8 * g + 4 * lhi + r;          // tile 0
        if (s0 < mv) { mv = s0; mi = e0; }
      }
#pragma unroll
    for (int g = 0; g < 4; ++g)
#pragma unroll
      for (int r = 0; r < 4; ++r) {
        const float s1 = a1A[4 * g + r] + a1B[4 * g + r];
        const int e1 = w * 64 + 32 + 8 * g + 4 * lhi + r;     // tile 1 (larger idx)
        if (s1 < mv) { mv = s1; mi = e1; }
      }
    // combine the two lane-halves (same query col l32, disjoint rows)
    {
      float ov = __shfl_xor(mv, 32, 64);
      int oi = __shfl_xor(mi, 32, 64);
      if (ov < mv || (ov == mv && oi < mi)) { mv = ov; mi = oi; }
    }
    if (lhi == 0) {
      smin[w][qt * 32 + l32] = mv;
      simin[w][qt * 32 + l32] = mi;
    }
  }
  __syncthreads();                       // barrier #2: all smin written

  // ---- combine 8 waves (disjoint ascending entry ranges; tie -> lower index) ----
  if (t < 256) {
    float bv = smin[0][t]; int bi = simin[0][t];
#pragma unroll
    for (int ww = 1; ww < 8; ++ww) {
      float v = smin[ww][t]; int ii = simin[ww][t];
      if (v < bv || (v == bv && ii < bi)) { bv = v; bi = ii; }
    }
    best[t] = bi;
  }
  __syncthreads();

  // ---- gather: exact fp32 rows (L2-hot codebook), coalesced NT stores ----
#pragma unroll
  for (int i2 = 0; i2 < 8; ++i2) {
    const int f = t + 512 * i2;          // 4096 f32x4 per block
    const int q = f >> 4, g = f & 15;
    const int e = best[q];
    f32x4 v = *(const f32x4*)(codebook + e * D_ + g * 4);
    __builtin_nontemporal_store(v, (f32x4*)(out + (qb + q) * D_ + g * 4));
  }
}

extern "C" void kernel_launch(void* const* d_in, const int* in_sizes, int n_in,
                              void* d_out, int out_size, void* d_ws, size_t ws_size,
                              hipStream_t stream) {
  const float* codes = (const float*)d_in[0];
  const float* codebook = (const float*)d_in[1];
  float* out = (float*)d_out;
  const int Q = in_sizes[0] / D_;        // 65536
  const int grid = Q / 256;              // 256
  vq_fused<<<grid, 512, 0, stream>>>(codes, codebook, out);
}

// Round 18
// 23.965 us; speedup vs baseline: 1.6872x; 1.0639x over previous
//
#include <hip/hip_runtime.h>

typedef __attribute__((ext_vector_type(4))) float f32x4;
typedef __attribute__((ext_vector_type(16))) float f32x16;
typedef __attribute__((ext_vector_type(8))) _Float16 f16x8;

#define D_ 64
#define K_ 512

// 2-limb f16 (a = hi + lo, 22 mantissa bits) on mfma_f32_32x32x16_f16.
// K-space = 128 limbs in 8 k-blocks of 16: kb 0-3 = hi(dims 16kb..16kb+15),
// kb 4-7 = lo. Operand slot (lane>>5, s) holds dim-pos (lane>>5)*8 + s —
// IDENTICAL builder for entries (A) and queries (B) => within-k-block
// permutation cancels in A.B (validated r15-r17: absmax 0.0).
// Queries NEGATED; acc seeded with 0.5||e||^2: score = 0.5||e||^2 - c.e
// (lo.lo dropped, ~1.5e-5).
// C/D (HW m74/m101): col = lane&31 = query, row = (reg&3)+8*(reg>>2)+4*(lane>>5).
//
// r18 = r15 + software-pipelined qf: explicit double-buffer, qt+1's 8
// ds_read_b128 issued BEFORE qt's MFMA burst (latency hides under MFMA) +
// s_setprio(1) around the MFMA clusters (waves are barrier-free/drifting ->
// role-diverse, T5's precondition). Attacks the fold/DS window that idles the
// MFMA pipe at ~50% (r7/r13/r17 proved waves/chains don't fix it).
__global__ __launch_bounds__(512, 2)
void vq_fused(const float* __restrict__ codes,
              const float* __restrict__ codebook,
              float* __restrict__ out) {
  __shared__ _Float16 Af[256 * 128];     // 64 KB query frags
  __shared__ float esq_s[K_];            // 2 KB
  __shared__ float smin[8][256];         // 8 KB
  __shared__ int   simin[8][256];        // 8 KB
  __shared__ int   best[256];            // 1 KB

  const int t = threadIdx.x;
  const int w = t >> 6, l = t & 63;
  const int l32 = l & 31, lhi = l >> 5;
  const long long qb = (long long)blockIdx.x * 256;

  // ---- issue query loads first: thread -> query ql, dims dhalf..dhalf+31 ----
  const int ql = t >> 1, dhalf = (t & 1) * 32;
  const float* asrc = codes + (qb + ql) * D_ + dhalf;
  f32x4 av[8];
#pragma unroll
  for (int g = 0; g < 8; ++g) av[g] = *(const f32x4*)(asrc + 4 * g);

  // ---- build ef frags + 0.5||e||^2 (wave owns entries 64w..64w+63) ----
  f16x8 ef[2][8];                        // [tile][kb] kb0-3 hi, kb4-7 lo
#pragma unroll
  for (int i = 0; i < 2; ++i) {
    const int e = w * 64 + i * 32 + l32;
    float es = 0.f;
#pragma unroll
    for (int kb = 0; kb < 4; ++kb) {
      const float* src = codebook + e * D_ + kb * 16 + lhi * 8;
      f32x4 v0 = *(const f32x4*)src;
      f32x4 v1 = *(const f32x4*)(src + 4);
#pragma unroll
      for (int s = 0; s < 8; ++s) {
        float a = (s < 4) ? v0[s & 3] : v1[s & 3];
        es += a * a;
        _Float16 h = (_Float16)a;
        ef[i][kb][s] = h;
        ef[i][4 + kb][s] = (_Float16)(a - (float)h);
      }
    }
    es += __shfl_xor(es, 32, 64);        // lane pair covers all 64 dims
    if (lhi == 0) esq_s[e] = 0.5f * es;
  }

  // ---- stage queries: negated 2-limb frags, 8 x ds_write_b128 ----
  {
    const int kbs = (t & 1) * 2;         // thread's two k-blocks
    const int qtile = ql >> 5, qr = ql & 31;
#pragma unroll
    for (int kk = 0; kk < 2; ++kk)
#pragma unroll
      for (int ph = 0; ph < 2; ++ph) {
        f16x8 wh, wl;
#pragma unroll
        for (int s = 0; s < 8; ++s) {
          float na = -av[kk * 4 + ph * 2 + (s >> 2)][s & 3];
          _Float16 h = (_Float16)na;
          wh[s] = h;
          wl[s] = (_Float16)(na - (float)h);
        }
        _Float16* dst = Af + qtile * 4096 + (kbs + kk) * 512 + ph * 256 + qr * 8;
        *(f16x8*)dst = wh;               // hi k-block
        *(f16x8*)(dst + 2048) = wl;      // lo k-block (kb+4)
      }
  }
  __syncthreads();                       // barrier #1: Af + esq_s ready

  // per-lane 0.5||e||^2 for C/D rows: row(reg) = (reg&3) + 8*(reg>>2) + 4*lhi
  f32x4 esqr[2][4];
#pragma unroll
  for (int i = 0; i < 2; ++i)
#pragma unroll
    for (int g = 0; g < 4; ++g)
      esqr[i][g] = *(const f32x4*)(esq_s + w * 64 + i * 32 + 8 * g + 4 * lhi);

  const _Float16* qbase = Af + lhi * 256 + l32 * 8;

  // fold + combine + smin-write for one finished q-tile
  auto finish = [&](const f32x16& a0, const f32x16& a1, int qt) {
    float mv = 3.4e38f; int mi = 0;
#pragma unroll
    for (int g = 0; g < 4; ++g)
#pragma unroll
      for (int r = 0; r < 4; ++r) {
        const int e0 = w * 64 + 8 * g + 4 * lhi + r;          // tile 0
        if (a0[4 * g + r] < mv) { mv = a0[4 * g + r]; mi = e0; }
      }
#pragma unroll
    for (int g = 0; g < 4; ++g)
#pragma unroll
      for (int r = 0; r < 4; ++r) {
        const int e1 = w * 64 + 32 + 8 * g + 4 * lhi + r;     // tile 1 (larger idx)
        if (a1[4 * g + r] < mv) { mv = a1[4 * g + r]; mi = e1; }
      }
    float ov = __shfl_xor(mv, 32, 64);
    int oi = __shfl_xor(mi, 32, 64);
    if (ov < mv || (ov == mv && oi < mi)) { mv = ov; mi = oi; }
    if (lhi == 0) {
      smin[w][qt * 32 + l32] = mv;
      simin[w][qt * 32 + l32] = mi;
    }
  };

  auto mfma24 = [&](const f16x8* qf, f32x16& a0, f32x16& a1) {
#pragma unroll
    for (int g = 0; g < 4; ++g)
#pragma unroll
      for (int r = 0; r < 4; ++r) {
        a0[4 * g + r] = esqr[0][g][r];   // C seed: 0.5||e||^2
        a1[4 * g + r] = esqr[1][g][r];
      }
    __builtin_amdgcn_s_setprio(1);
#pragma unroll
    for (int kb = 0; kb < 4; ++kb) {     // eh . (-ch)
      a0 = __builtin_amdgcn_mfma_f32_32x32x16_f16(ef[0][kb], qf[kb], a0, 0, 0, 0);
      a1 = __builtin_amdgcn_mfma_f32_32x32x16_f16(ef[1][kb], qf[kb], a1, 0, 0, 0);
    }
#pragma unroll
    for (int kb = 0; kb < 4; ++kb) {     // eh . (-cl)
      a0 = __builtin_amdgcn_mfma_f32_32x32x16_f16(ef[0][kb], qf[4 + kb], a0, 0, 0, 0);
      a1 = __builtin_amdgcn_mfma_f32_32x32x16_f16(ef[1][kb], qf[4 + kb], a1, 0, 0, 0);
    }
#pragma unroll
    for (int kb = 0; kb < 4; ++kb) {     // el . (-ch)
      a0 = __builtin_amdgcn_mfma_f32_32x32x16_f16(ef[0][4 + kb], qf[kb], a0, 0, 0, 0);
      a1 = __builtin_amdgcn_mfma_f32_32x32x16_f16(ef[1][4 + kb], qf[kb], a1, 0, 0, 0);
    }
    __builtin_amdgcn_s_setprio(0);
  };

  // ---- main loop: 8 q-tiles, software-pipelined qf double-buffer ----
  f16x8 qfA[8], qfB[8];
#pragma unroll
  for (int kb = 0; kb < 8; ++kb)         // preload qt=0
    qfA[kb] = *(const f16x8*)(qbase + 0 * 4096 + kb * 512);

#pragma unroll
  for (int qt = 0; qt < 8; qt += 2) {
    // prefetch qt+1 BEFORE the qt MFMA burst (DS latency hides under MFMA)
#pragma unroll
    for (int kb = 0; kb < 8; ++kb)
      qfB[kb] = *(const f16x8*)(qbase + (qt + 1) * 4096 + kb * 512);

    f32x16 a0, a1;
    mfma24(qfA, a0, a1);

    if (qt + 2 < 8) {                    // prefetch qt+2 before qt+1's burst
#pragma unroll
      for (int kb = 0; kb < 8; ++kb)
        qfA[kb] = *(const f16x8*)(qbase + (qt + 2) * 4096 + kb * 512);
    }
    finish(a0, a1, qt);                  // fold overlaps qt+1's MFMA issue window

    f32x16 b0, b1;
    mfma24(qfB, b0, b1);
    finish(b0, b1, qt + 1);
  }
  __syncthreads();                       // barrier #2: all smin written

  // ---- combine 8 waves (disjoint ascending entry ranges; tie -> lower index) ----
  if (t < 256) {
    float bv = smin[0][t]; int bi = simin[0][t];
#pragma unroll
    for (int ww = 1; ww < 8; ++ww) {
      float v = smin[ww][t]; int ii = simin[ww][t];
      if (v < bv || (v == bv && ii < bi)) { bv = v; bi = ii; }
    }
    best[t] = bi;
  }
  __syncthreads();

  // ---- gather: exact fp32 rows (L2-hot codebook), coalesced NT stores ----
#pragma unroll
  for (int i2 = 0; i2 < 8; ++i2) {
    const int f = t + 512 * i2;          // 4096 f32x4 per block
    const int q = f >> 4, g = f & 15;
    const int e = best[q];
    f32x4 v = *(const f32x4*)(codebook + e * D_ + g * 4);
    __builtin_nontemporal_store(v, (f32x4*)(out + (qb + q) * D_ + g * 4));
  }
}

extern "C" void kernel_launch(void* const* d_in, const int* in_sizes, int n_in,
                              void* d_out, int out_size, void* d_ws, size_t ws_size,
                              hipStream_t stream) {
  const float* codes = (const float*)d_in[0];
  const float* codebook = (const float*)d_in[1];
  float* out = (float*)d_out;
  const int Q = in_sizes[0] / D_;        // 65536
  const int grid = Q / 256;              // 256
  vq_fused<<<grid, 512, 0, stream>>>(codes, codebook, out);
}